// Round 9
// baseline (1517.667 us; speedup 1.0000x reference)
//
#include <hip/hip_runtime.h>

#define N_NODES    100000
#define N_EDGES    1600000
#define DIM        64
#define NUM_GRAPHS 1000
#define PAD        72      // padded LDS row (bf16 units)

// ---- bucket-sort CSR parameters ----
#define SLICES     512
#define SLICE_E    3125    // N_EDGES / SLICES exact
#define NBUCK      782     // ceil(N_NODES / 128), bucket = dst >> 7
#define CONV_BLK   3125    // (N_NODES*DIM/8)/256 exactly

typedef __attribute__((ext_vector_type(8))) short bf16x8;
typedef __attribute__((ext_vector_type(4))) float f32x4;

// bf16 helpers (round-to-nearest-even)
__device__ __forceinline__ unsigned short f2bf(float f) {
    unsigned int b = __float_as_uint(f);
    b += 0x7FFFu + ((b >> 16) & 1u);
    return (unsigned short)(b >> 16);
}

__device__ __forceinline__ float4 ntload_f4(const float* p) {
    f32x4 v = __builtin_nontemporal_load((const f32x4*)p);
    return make_float4(v.x, v.y, v.z, v.w);
}

// ---------------------------------------------------------------------------
// prep: role 1 (blocks < SLICES): per-slice bucket histogram of dst.
//       role 2: x -> bf16 table conversion (NT loads: read-once stream).
// (round-7 verbatim)
// ---------------------------------------------------------------------------
__global__ __launch_bounds__(256) void prep(
    const int* __restrict__ ei, const float* __restrict__ x,
    int* __restrict__ hist, int* __restrict__ bucketTotal,
    unsigned short* __restrict__ x16)
{
    __shared__ int lh[NBUCK];
    int blk = blockIdx.x, t = threadIdx.x;
    if (blk < SLICES) {
        for (int i = t; i < NBUCK; i += 256) lh[i] = 0;
        __syncthreads();
        const int* dsts = ei + N_EDGES + blk * SLICE_E;
        for (int k = t; k < SLICE_E; k += 256)
            atomicAdd(&lh[dsts[k] >> 7], 1);
        __syncthreads();
        for (int i = t; i < NBUCK; i += 256) {
            int h = lh[i];
            hist[blk * NBUCK + i] = h;
            if (h) atomicAdd(&bucketTotal[i], h);
        }
    } else {
        int tt = (blk - SLICES) * 256 + t;
        if (tt < N_NODES * DIM / 8) {
            int base = tt * 8;
            float4 f0 = ntload_f4(x + base);
            float4 f1 = ntload_f4(x + base + 4);
            uint4 o;
            o.x = (unsigned)f2bf(f0.x) | ((unsigned)f2bf(f0.y) << 16);
            o.y = (unsigned)f2bf(f0.z) | ((unsigned)f2bf(f0.w) << 16);
            o.z = (unsigned)f2bf(f1.x) | ((unsigned)f2bf(f1.y) << 16);
            o.w = (unsigned)f2bf(f1.z) | ((unsigned)f2bf(f1.w) << 16);
            *(uint4*)(x16 + base) = o;
        }
    }
}

// ---------------------------------------------------------------------------
// C2a: exclusive scan of bucketTotal -> bucketStart[0..NBUCK] (verbatim)
// ---------------------------------------------------------------------------
__global__ __launch_bounds__(1024) void csr_c2a(
    const int* __restrict__ bucketTotal, int* __restrict__ bucketStart)
{
    __shared__ int sc[1024];
    int t = threadIdx.x;
    int v = (t < NBUCK) ? bucketTotal[t] : 0;
    sc[t] = v;
    __syncthreads();
    for (int o = 1; o < 1024; o <<= 1) {
        int u = (t >= o) ? sc[t - o] : 0;
        __syncthreads();
        sc[t] += u;
        __syncthreads();
    }
    if (t < NBUCK) bucketStart[t] = sc[t] - v;
    if (t == NBUCK - 1) bucketStart[NBUCK] = sc[t];
}

// ---------------------------------------------------------------------------
// C2b: per-bucket exclusive scan over slices (verbatim)
// ---------------------------------------------------------------------------
__global__ __launch_bounds__(512) void csr_c2b(
    const int* __restrict__ hist, const int* __restrict__ bucketStart,
    int* __restrict__ off)
{
    __shared__ int sc[512];
    int b = blockIdx.x, t = threadIdx.x;
    int v = hist[t * NBUCK + b];
    sc[t] = v;
    __syncthreads();
    for (int o = 1; o < 512; o <<= 1) {
        int u = (t >= o) ? sc[t - o] : 0;
        __syncthreads();
        sc[t] += u;
        __syncthreads();
    }
    off[b * SLICES + t] = bucketStart[b] + sc[t] - v;
}

// ---------------------------------------------------------------------------
// C3: per-slice LDS counting-sort by bucket, 512 threads (round-7 verbatim).
// tmp record: {(dlocal<<17)|src, attr_bits}, bucket-grouped.
// ---------------------------------------------------------------------------
__global__ __launch_bounds__(512) void csr_c3(
    const int* __restrict__ ei, const float* __restrict__ ea,
    const int* __restrict__ hist, const int* __restrict__ off,
    int2* __restrict__ tmp)
{
    __shared__ int2 staging[SLICE_E];
    __shared__ int  lstart[NBUCK + 1];
    __shared__ int  garr[NBUCK];
    __shared__ int  lcur[NBUCK];
    __shared__ unsigned short barr[SLICE_E];
    __shared__ int  part[512];

    int s = blockIdx.x, t = threadIdx.x;

    int h[2];
    int mysum = 0;
    #pragma unroll
    for (int j = 0; j < 2; ++j) {
        int b = 2 * t + j;
        h[j] = (b < NBUCK) ? hist[s * NBUCK + b] : 0;
        mysum += h[j];
    }
    part[t] = mysum;
    for (int i = t; i < NBUCK; i += 512) {
        garr[i] = off[i * SLICES + s];
        lcur[i] = 0;
    }
    __syncthreads();
    for (int o = 1; o < 512; o <<= 1) {
        int u = (t >= o) ? part[t - o] : 0;
        __syncthreads();
        part[t] += u;
        __syncthreads();
    }
    int run = part[t] - mysum;
    #pragma unroll
    for (int j = 0; j < 2; ++j) {
        int b = 2 * t + j;
        if (b < NBUCK) lstart[b] = run;
        run += h[j];
    }
    if (t == 0) lstart[NBUCK] = SLICE_E;
    __syncthreads();

    #pragma unroll
    for (int j = 0; j < 2; ++j) {
        int b = 2 * t + j;
        if (b < NBUCK)
            for (int i = lstart[b]; i < lstart[b + 1]; ++i)
                barr[i] = (unsigned short)b;
    }
    __syncthreads();

    for (int k = t; k < SLICE_E; k += 512) {
        int e   = s * SLICE_E + k;
        int src = ei[e];
        int dst = ei[N_EDGES + e];
        float a = ea[e];
        int b   = dst >> 7;
        int p   = lstart[b] + atomicAdd(&lcur[b], 1);
        staging[p] = make_int2(((dst & 127) << 17) | src, __float_as_int(a));
    }
    __syncthreads();

    for (int i = t; i < SLICE_E; i += 512) {
        int b = barr[i];
        tmp[garr[b] + (i - lstart[b])] = staging[i];
    }
}

// ---------------------------------------------------------------------------
// gine_bucket: one block per 128-node bucket. Consumes bucket-grouped tmp
// directly (node-UNSORTED — c4 deleted). Phase B scatter-aggregates messages
// into LDS hacc[128][64] via ds_add_f32; phase C adds self + converts to bf16
// in place; phase D runs the GIN MLP (mlp128's verified MFMA code, A from LDS).
// ---------------------------------------------------------------------------
template<bool SELF32>
__global__ __launch_bounds__(512, 4) void gine_bucket(
    const uint2* __restrict__ g2,            // [N*16] gather rows (bf16x4 units)
    const float* __restrict__ self32,        // [N,64] fp32 self (SELF32)
    const unsigned short* __restrict__ selfb,// [N,64] bf16 self (!SELF32)
    const int* __restrict__ bucketStart,
    const int2* __restrict__ tmp,            // {dlocal<<17|src, attr}
    const float* __restrict__ We, const float* __restrict__ be,
    const float* __restrict__ Wa, const float* __restrict__ ba,
    const float* __restrict__ Wb, const float* __restrict__ bb,
    unsigned short* __restrict__ hout)       // [N,64] bf16
{
    __shared__ float hacc[128 * 64];         // 32768 B
    __shared__ short t16[128 * PAD];         // 18432 B
    short* hbf = (short*)hacc;               // bf16 overlay after phase C

    int t = threadIdx.x;
    int b = blockIdx.x;
    int node0 = b << 7;
    int nn = min(128, N_NODES - node0);

    int lane = t & 63;
    int quad = lane >> 4;        // 0..3 within wave (MFMA)
    int l15  = lane & 15;
    int d0   = l15 * 4;
    float4 wp = *(const float4*)(We + d0);
    float4 bp = *(const float4*)(be + d0);

    // MLP weight fragments in registers (mlp128-verified layout)
    int wave  = t >> 6;
    int ntile = wave >> 1;       // 0..3 col-tile
    int mhalf = wave & 1;        // 0..1 row-half
    int col   = ntile * 16 + l15;
    bf16x8 fragA[2], fragB[2];
    #pragma unroll
    for (int s = 0; s < 2; ++s) {
        #pragma unroll
        for (int j = 0; j < 8; ++j) {
            int k = s * 32 + quad * 8 + j;
            fragA[s][j] = (short)f2bf(Wa[k * 64 + col]);
            fragB[s][j] = (short)f2bf(Wb[k * 64 + col]);
        }
    }
    float bav = ba[col], bbv = bb[col];

    // ---- phase A: zero accumulator ----
    for (int i = t; i < 128 * 64; i += 512) hacc[i] = 0.f;
    __syncthreads();

    // ---- phase B: scatter-aggregate records (each quad: 4 records/iter) ----
    int lo  = bucketStart[b];
    int cnt = bucketStart[b + 1] - lo;
    int gq  = t >> 4;            // global quad id 0..31

    #define REC(rr, uu, cond)                                                    \
    {                                                                            \
        float s  = (cond) ? 1.f : 0.f;                                           \
        float av = __int_as_float(rr.y);                                         \
        int   dl = ((unsigned)rr.x) >> 17;                                       \
        float* hp = &hacc[dl * 64 + d0];                                         \
        float e0 = __uint_as_float(uu.x << 16);                                  \
        float e1 = __uint_as_float(uu.x & 0xFFFF0000u);                          \
        float e2 = __uint_as_float(uu.y << 16);                                  \
        float e3 = __uint_as_float(uu.y & 0xFFFF0000u);                          \
        atomicAdd(hp + 0, s * fmaxf(e0 + fmaf(av, wp.x, bp.x), 0.f));            \
        atomicAdd(hp + 1, s * fmaxf(e1 + fmaf(av, wp.y, bp.y), 0.f));            \
        atomicAdd(hp + 2, s * fmaxf(e2 + fmaf(av, wp.z, bp.z), 0.f));            \
        atomicAdd(hp + 3, s * fmaxf(e3 + fmaf(av, wp.w, bp.w), 0.f));            \
    }
    for (int k0 = gq * 4; k0 < cnt; k0 += 128) {
        int2 r0 = tmp[lo + k0];
        int2 r1 = tmp[lo + ((k0 + 1 < cnt) ? k0 + 1 : k0)];
        int2 r2 = tmp[lo + ((k0 + 2 < cnt) ? k0 + 2 : k0)];
        int2 r3 = tmp[lo + ((k0 + 3 < cnt) ? k0 + 3 : k0)];
        uint2 u0 = g2[(r0.x & 0x1FFFF) * 16 + l15];
        uint2 u1 = g2[(r1.x & 0x1FFFF) * 16 + l15];
        uint2 u2 = g2[(r2.x & 0x1FFFF) * 16 + l15];
        uint2 u3 = g2[(r3.x & 0x1FFFF) * 16 + l15];
        REC(r0, u0, true)
        REC(r1, u1, k0 + 1 < cnt)
        REC(r2, u2, k0 + 2 < cnt)
        REC(r3, u3, k0 + 3 < cnt)
    }
    #undef REC
    __syncthreads();

    // ---- phase C: add self, convert to bf16 in place (hacc -> hbf) ----
    {
        int r   = t >> 2;            // 0..127
        int dlo = (t & 3) * 16;
        float v[16];
        #pragma unroll
        for (int i = 0; i < 16; ++i) v[i] = hacc[r * 64 + dlo + i];
        if (r < nn) {
            int node = node0 + r;
            if (SELF32) {
                const float* sp = self32 + (size_t)node * DIM + dlo;
                #pragma unroll
                for (int i = 0; i < 16; ++i) v[i] += sp[i];
            } else {
                const uint4* up = (const uint4*)(selfb + (size_t)node * DIM + dlo);
                uint4 A = up[0], B = up[1];
                unsigned w[8] = {A.x, A.y, A.z, A.w, B.x, B.y, B.z, B.w};
                #pragma unroll
                for (int i = 0; i < 8; ++i) {
                    v[2 * i]     += __uint_as_float(w[i] << 16);
                    v[2 * i + 1] += __uint_as_float(w[i] & 0xFFFF0000u);
                }
            }
        }
        __syncthreads();             // all reads of hacc done before overlay writes
        uint4 o0, o1;
        o0.x = (unsigned)f2bf(v[0])  | ((unsigned)f2bf(v[1])  << 16);
        o0.y = (unsigned)f2bf(v[2])  | ((unsigned)f2bf(v[3])  << 16);
        o0.z = (unsigned)f2bf(v[4])  | ((unsigned)f2bf(v[5])  << 16);
        o0.w = (unsigned)f2bf(v[6])  | ((unsigned)f2bf(v[7])  << 16);
        o1.x = (unsigned)f2bf(v[8])  | ((unsigned)f2bf(v[9])  << 16);
        o1.y = (unsigned)f2bf(v[10]) | ((unsigned)f2bf(v[11]) << 16);
        o1.z = (unsigned)f2bf(v[12]) | ((unsigned)f2bf(v[13]) << 16);
        o1.w = (unsigned)f2bf(v[14]) | ((unsigned)f2bf(v[15]) << 16);
        *(uint4*)&hbf[r * PAD + dlo]     = o0;
        *(uint4*)&hbf[r * PAD + dlo + 8] = o1;
    }
    __syncthreads();

    // ---- phase D: GIN MLP (mlp128-verified), A operand from hbf LDS ----
    #pragma unroll
    for (int mt = 0; mt < 4; ++mt) {
        int rbase = mhalf * 64 + mt * 16;
        f32x4 acc = {bav, bav, bav, bav};
        #pragma unroll
        for (int s = 0; s < 2; ++s) {
            bf16x8 a = *(const bf16x8*)&hbf[(rbase + l15) * PAD + s * 32 + quad * 8];
            acc = __builtin_amdgcn_mfma_f32_16x16x32_bf16(a, fragA[s], acc, 0, 0, 0);
        }
        #pragma unroll
        for (int r = 0; r < 4; ++r)
            t16[(rbase + quad * 4 + r) * PAD + col] = (short)f2bf(fmaxf(acc[r], 0.f));
    }
    __syncthreads();

    #pragma unroll
    for (int mt = 0; mt < 4; ++mt) {
        int rbase = mhalf * 64 + mt * 16;
        f32x4 acc2 = {bbv, bbv, bbv, bbv};
        #pragma unroll
        for (int s = 0; s < 2; ++s) {
            bf16x8 a = *(const bf16x8*)&t16[(rbase + l15) * PAD + s * 32 + quad * 8];
            acc2 = __builtin_amdgcn_mfma_f32_16x16x32_bf16(a, fragB[s], acc2, 0, 0, 0);
        }
        #pragma unroll
        for (int r = 0; r < 4; ++r) {
            int row = rbase + quad * 4 + r;
            if (node0 + row < N_NODES)
                hout[(size_t)(node0 + row) * DIM + col] = (unsigned short)f2bf(fmaxf(acc2[r], 0.f));
        }
    }
}

// ---------------------------------------------------------------------------
// Fused pooling + classifier (unchanged).
// ---------------------------------------------------------------------------
__device__ __forceinline__ int lbound(const int* __restrict__ a, int key) {
    int lo = 0, hi = N_NODES;
    while (lo < hi) {
        int mid = (lo + hi) >> 1;
        if (a[mid] < key) lo = mid + 1; else hi = mid;
    }
    return lo;
}

__global__ __launch_bounds__(256) void pool_cls(
    const unsigned int* __restrict__ B16b,
    const int* __restrict__ batch,
    const float* __restrict__ Wc1,  const float* __restrict__ bc1,
    const float* __restrict__ Wc2,  const float* __restrict__ bc2,
    float* __restrict__ out)
{
    __shared__ float sW[64 * 64];
    __shared__ float sp[4][64];

    int t = threadIdx.x;
    for (int i = t; i < 64 * 64; i += 256) sW[i] = Wc1[i];

    int nl   = t >> 6;
    int lane = t & 63;
    int g    = blockIdx.x * 4 + nl;

    int p = lane & 31, h = lane >> 5;
    if (g < NUM_GRAPHS) {
        int s = lbound(batch, g);
        int e = lbound(batch, g + 1);
        float2 sum = make_float2(0.f, 0.f);
        for (int i = s + h; i < e; i += 2) {
            unsigned u = B16b[(size_t)i * 32 + p];
            sum.x += __uint_as_float(u << 16);
            sum.y += __uint_as_float(u & 0xFFFF0000u);
        }
        sum.x += __shfl_xor(sum.x, 32);
        sum.y += __shfl_xor(sum.y, 32);
        if (h == 0) {
            float inv = 1.f / (float)max(e - s, 1);
            sp[nl][2 * p]     = sum.x * inv;
            sp[nl][2 * p + 1] = sum.y * inv;
        }
    } else if (h == 0) {
        sp[nl][2 * p] = 0.f;
        sp[nl][2 * p + 1] = 0.f;
    }
    __syncthreads();

    float acc = bc1[lane];
    #pragma unroll
    for (int k = 0; k < 64; ++k)
        acc = fmaf(sp[nl][k], sW[k * 64 + lane], acc);
    float tv = fmaxf(acc, 0.f) * Wc2[lane];

    #pragma unroll
    for (int off = 32; off > 0; off >>= 1)
        tv += __shfl_down(tv, off);

    if (lane == 0 && g < NUM_GRAPHS) out[g] = tv + bc2[0];
}

extern "C" void kernel_launch(void* const* d_in, const int* in_sizes, int n_in,
                              void* d_out, int out_size, void* d_ws, size_t ws_size,
                              hipStream_t stream) {
    const float* x     = (const float*)d_in[0];
    const int*   ei    = (const int*)  d_in[1];
    const float* ea    = (const float*)d_in[2];
    const int*   batch = (const int*)  d_in[3];
    const float* W1a = (const float*)d_in[4];
    const float* b1a = (const float*)d_in[5];
    const float* W1b = (const float*)d_in[6];
    const float* b1b = (const float*)d_in[7];
    const float* We1 = (const float*)d_in[8];
    const float* be1 = (const float*)d_in[9];
    const float* W2a = (const float*)d_in[10];
    const float* b2a = (const float*)d_in[11];
    const float* W2b = (const float*)d_in[12];
    const float* b2b = (const float*)d_in[13];
    const float* We2 = (const float*)d_in[14];
    const float* be2 = (const float*)d_in[15];
    const float* Wc1 = (const float*)d_in[16];
    const float* bc1 = (const float*)d_in[17];
    const float* Wc2 = (const float*)d_in[18];
    const float* bc2 = (const float*)d_in[19];

    // workspace layout (~54.6 MB). tmp is read by BOTH gine layers -> own region.
    int2*           tmp    = (int2*)d_ws;                            // [E] 12.8MB
    unsigned short* x16    = (unsigned short*)(tmp + N_EDGES);       // [N*64]
    unsigned short* B16    = x16 + (size_t)N_NODES * DIM;            // [N*64] h1
    unsigned short* B16b   = B16 + (size_t)N_NODES * DIM;            // [N*64] h2
    int*            hist   = (int*)(B16b + (size_t)N_NODES * DIM);   // [SLICES*NBUCK]
    int*            off    = hist + SLICES * NBUCK;                  // [NBUCK*SLICES]
    int*            bucketTotal = off + NBUCK * SLICES;              // [NBUCK]
    int*            bucketStart = bucketTotal + NBUCK;               // [NBUCK+1]

    hipMemsetAsync(bucketTotal, 0, NBUCK * sizeof(int), stream);

    // ---- bucket-grouped edge build (c4 deleted) ----
    prep<<<SLICES + CONV_BLK, 256, 0, stream>>>(ei, x, hist, bucketTotal, x16);
    csr_c2a<<<1, 1024, 0, stream>>>(bucketTotal, bucketStart);
    csr_c2b<<<NBUCK, 512, 0, stream>>>(hist, bucketStart, off);
    csr_c3<<<SLICES, 512, 0, stream>>>(ei, ea, hist, off, tmp);

    // ---- layer 1: bucket aggregate (gather x16, self fp32 x) + MLP -> B16 ----
    gine_bucket<true><<<NBUCK, 512, 0, stream>>>(
        (const uint2*)x16, x, nullptr, bucketStart, tmp,
        We1, be1, W1a, b1a, W1b, b1b, B16);

    // ---- layer 2: bucket aggregate (gather B16, self B16) + MLP -> B16b ----
    gine_bucket<false><<<NBUCK, 512, 0, stream>>>(
        (const uint2*)B16, nullptr, B16, bucketStart, tmp,
        We2, be2, W2a, b2a, W2b, b2b, B16b);

    // ---- fused pooling + classifier ----
    pool_cls<<<(NUM_GRAPHS + 3) / 4, 256, 0, stream>>>(
        (const unsigned int*)B16b, batch, Wc1, bc1, Wc2, bc2, (float*)d_out);
}

// Round 10
// 296.429 us; speedup vs baseline: 5.1198x; 5.1198x over previous
//
#include <hip/hip_runtime.h>

#define N_NODES    100000
#define N_EDGES    1600000
#define DIM        64
#define NUM_GRAPHS 1000
#define CONV_BLK   3125    // (N_NODES*DIM/8)/256 exactly
#define PAD        72      // padded LDS row (bf16 units)

// ---- bucket-sort CSR parameters ----
#define SLICES     512
#define SLICE_E    3125    // N_EDGES / SLICES exact
#define NBUCK      782     // ceil(N_NODES / 128), bucket = dst >> 7
#define CAP4       3072    // max records per bucket (mean 2046, sd ~45)

typedef __attribute__((ext_vector_type(8))) short bf16x8;
typedef __attribute__((ext_vector_type(4))) float f32x4;

// bf16 helpers (round-to-nearest-even)
__device__ __forceinline__ unsigned short f2bf(float f) {
    unsigned int b = __float_as_uint(f);
    b += 0x7FFFu + ((b >> 16) & 1u);
    return (unsigned short)(b >> 16);
}

__device__ __forceinline__ float4 ntload_f4(const float* p) {
    f32x4 v = __builtin_nontemporal_load((const f32x4*)p);
    return make_float4(v.x, v.y, v.z, v.w);
}

// ---------------------------------------------------------------------------
// prep: role 1 (blocks < SLICES): per-slice bucket histogram of dst.
//       role 2: x -> bf16 table conversion. (round-7 verbatim)
// ---------------------------------------------------------------------------
__global__ __launch_bounds__(256) void prep(
    const int* __restrict__ ei, const float* __restrict__ x,
    int* __restrict__ hist, int* __restrict__ bucketTotal,
    unsigned short* __restrict__ x16)
{
    __shared__ int lh[NBUCK];
    int blk = blockIdx.x, t = threadIdx.x;
    if (blk < SLICES) {
        for (int i = t; i < NBUCK; i += 256) lh[i] = 0;
        __syncthreads();
        const int* dsts = ei + N_EDGES + blk * SLICE_E;
        for (int k = t; k < SLICE_E; k += 256)
            atomicAdd(&lh[dsts[k] >> 7], 1);
        __syncthreads();
        for (int i = t; i < NBUCK; i += 256) {
            int h = lh[i];
            hist[blk * NBUCK + i] = h;
            if (h) atomicAdd(&bucketTotal[i], h);
        }
    } else {
        int tt = (blk - SLICES) * 256 + t;
        if (tt < N_NODES * DIM / 8) {
            int base = tt * 8;
            float4 f0 = ntload_f4(x + base);
            float4 f1 = ntload_f4(x + base + 4);
            uint4 o;
            o.x = (unsigned)f2bf(f0.x) | ((unsigned)f2bf(f0.y) << 16);
            o.y = (unsigned)f2bf(f0.z) | ((unsigned)f2bf(f0.w) << 16);
            o.z = (unsigned)f2bf(f1.x) | ((unsigned)f2bf(f1.y) << 16);
            o.w = (unsigned)f2bf(f1.z) | ((unsigned)f2bf(f1.w) << 16);
            *(uint4*)(x16 + base) = o;
        }
    }
}

// ---------------------------------------------------------------------------
// C2a: exclusive scan of bucketTotal -> bucketStart (verbatim)
// ---------------------------------------------------------------------------
__global__ __launch_bounds__(1024) void csr_c2a(
    const int* __restrict__ bucketTotal, int* __restrict__ bucketStart)
{
    __shared__ int sc[1024];
    int t = threadIdx.x;
    int v = (t < NBUCK) ? bucketTotal[t] : 0;
    sc[t] = v;
    __syncthreads();
    for (int o = 1; o < 1024; o <<= 1) {
        int u = (t >= o) ? sc[t - o] : 0;
        __syncthreads();
        sc[t] += u;
        __syncthreads();
    }
    if (t < NBUCK) bucketStart[t] = sc[t] - v;
    if (t == NBUCK - 1) bucketStart[NBUCK] = sc[t];
}

// ---------------------------------------------------------------------------
// C2b: per-bucket exclusive scan over slices (verbatim)
// ---------------------------------------------------------------------------
__global__ __launch_bounds__(512) void csr_c2b(
    const int* __restrict__ hist, const int* __restrict__ bucketStart,
    int* __restrict__ off)
{
    __shared__ int sc[512];
    int b = blockIdx.x, t = threadIdx.x;
    int v = hist[t * NBUCK + b];
    sc[t] = v;
    __syncthreads();
    for (int o = 1; o < 512; o <<= 1) {
        int u = (t >= o) ? sc[t - o] : 0;
        __syncthreads();
        sc[t] += u;
        __syncthreads();
    }
    off[b * SLICES + t] = bucketStart[b] + sc[t] - v;
}

// ---------------------------------------------------------------------------
// C3: per-slice LDS counting-sort by bucket, 512 threads (round-7 verbatim).
// tmp record: {(dlocal<<17)|src, attr_bits}, bucket-grouped.
// ---------------------------------------------------------------------------
__global__ __launch_bounds__(512) void csr_c3(
    const int* __restrict__ ei, const float* __restrict__ ea,
    const int* __restrict__ hist, const int* __restrict__ off,
    int2* __restrict__ tmp)
{
    __shared__ int2 staging[SLICE_E];
    __shared__ int  lstart[NBUCK + 1];
    __shared__ int  garr[NBUCK];
    __shared__ int  lcur[NBUCK];
    __shared__ unsigned short barr[SLICE_E];
    __shared__ int  part[512];

    int s = blockIdx.x, t = threadIdx.x;

    int h[2];
    int mysum = 0;
    #pragma unroll
    for (int j = 0; j < 2; ++j) {
        int b = 2 * t + j;
        h[j] = (b < NBUCK) ? hist[s * NBUCK + b] : 0;
        mysum += h[j];
    }
    part[t] = mysum;
    for (int i = t; i < NBUCK; i += 512) {
        garr[i] = off[i * SLICES + s];
        lcur[i] = 0;
    }
    __syncthreads();
    for (int o = 1; o < 512; o <<= 1) {
        int u = (t >= o) ? part[t - o] : 0;
        __syncthreads();
        part[t] += u;
        __syncthreads();
    }
    int run = part[t] - mysum;
    #pragma unroll
    for (int j = 0; j < 2; ++j) {
        int b = 2 * t + j;
        if (b < NBUCK) lstart[b] = run;
        run += h[j];
    }
    if (t == 0) lstart[NBUCK] = SLICE_E;
    __syncthreads();

    #pragma unroll
    for (int j = 0; j < 2; ++j) {
        int b = 2 * t + j;
        if (b < NBUCK)
            for (int i = lstart[b]; i < lstart[b + 1]; ++i)
                barr[i] = (unsigned short)b;
    }
    __syncthreads();

    for (int k = t; k < SLICE_E; k += 512) {
        int e   = s * SLICE_E + k;
        int src = ei[e];
        int dst = ei[N_EDGES + e];
        float a = ea[e];
        int b   = dst >> 7;
        int p   = lstart[b] + atomicAdd(&lcur[b], 1);
        staging[p] = make_int2(((dst & 127) << 17) | src, __float_as_int(a));
    }
    __syncthreads();

    for (int i = t; i < SLICE_E; i += 512) {
        int b = barr[i];
        tmp[garr[b] + (i - lstart[b])] = staging[i];
    }
}

// ---------------------------------------------------------------------------
// gine_sort: layer-1 GINE with c4's bucket sort FUSED in.
// One block per 128-node bucket (782 blocks x 512 threads).
// Phase 1 = c4 verbatim: sort tmp records by node into LDS staging;
//           write csr_e {src*16,attr} + rowptr to global for layer 2.
// Phase 2 = round-7 gine: 4 groups of 32 nodes; per-quad register
//           accumulate; edge records read from LDS staging (broadcast).
// Sort work of co-resident blocks hides under other blocks' gather stalls.
// ---------------------------------------------------------------------------
__global__ __launch_bounds__(512, 6) void gine_sort(
    const uint2* __restrict__ g2,      // [N*16] x16 gather rows (bf16x4 units)
    const float* __restrict__ self32,  // [N,64] fp32 x
    const int*   __restrict__ bucketStart,
    const int2*  __restrict__ tmp,     // {(dl<<17)|src, attr}, bucket-grouped
    int2* __restrict__ csr_e,          // out: {src*16, attr} node-sorted
    int*  __restrict__ rowptr,         // out: [N+1]
    const float* __restrict__ We, const float* __restrict__ be,
    const float* __restrict__ Wa, const float* __restrict__ ba,
    const float* __restrict__ Wb, const float* __restrict__ bb,
    unsigned int* __restrict__ out16)  // bf16x2 rows
{
    __shared__ int2 staging[CAP4];            // 24576 B
    __shared__ int  nh[128];
    __shared__ int  nscan[128];
    __shared__ int  ncur[128];                // 1536 B
    __shared__ short sWat[64 * PAD];          // 9216 B
    __shared__ short sWbt[64 * PAD];          // 9216 B
    __shared__ short h16[32 * PAD];           // 4608 B
    __shared__ short t16[32 * PAD];           // 4608 B  (total ~53.8 KB)

    int t = threadIdx.x;
    int b = blockIdx.x;
    int lo = bucketStart[b], hi = bucketStart[b + 1];
    int cnt = hi - lo;
    int node0 = b << 7;
    int nn = min(128, N_NODES - node0);

    // weights -> LDS (round-7 layout)
    for (int i = t; i < 4096; i += 512) {
        int k = i >> 6, n = i & 63;
        sWat[n * PAD + k] = (short)f2bf(Wa[i]);
        sWbt[n * PAD + k] = (short)f2bf(Wb[i]);
    }
    if (t < 128) { nh[t] = 0; ncur[t] = 0; }
    __syncthreads();

    // ---- phase 1: c4 sort (verbatim) ----
    int2 r[6];
    int nr = 0;
    for (int k = t; k < cnt; k += 512) {
        int2 v = tmp[lo + k];
        r[nr++] = v;
        atomicAdd(&nh[v.x >> 17], 1);
    }
    __syncthreads();

    if (t < 128) nscan[t] = nh[t];
    __syncthreads();
    for (int o = 1; o < 128; o <<= 1) {
        int u = (t >= o && t < 128) ? nscan[t - o] : 0;
        __syncthreads();
        if (t < 128) nscan[t] += u;
        __syncthreads();
    }
    if (t < 128) nscan[t] -= nh[t];           // exclusive (local start)
    __syncthreads();

    if (t < nn) rowptr[node0 + t] = lo + nscan[t];
    if (b == NBUCK - 1 && t == 0) rowptr[N_NODES] = N_EDGES;

    for (int k = 0; k < nr; ++k) {
        int dl = r[k].x >> 17;
        int p  = nscan[dl] + atomicAdd(&ncur[dl], 1);
        staging[p] = r[k];
    }
    __syncthreads();

    // write node-sorted csr_e for layer 2 (coalesced)
    for (int i = t; i < cnt; i += 512) {
        int2 v = staging[i];
        csr_e[lo + i] = make_int2((v.x & 0x1FFFF) << 4, v.y);
    }

    // ---- phase 2: round-7 gine, records from LDS staging ----
    int wave = t >> 6;
    int lane = t & 63;
    int quad = lane >> 4;
    int l15  = lane & 15;
    int slot = wave * 4 + quad;               // 0..31
    int d0   = l15 * 4;
    float4 wp = *(const float4*)(We + d0);
    float4 bp = *(const float4*)(be + d0);
    int mtile = wave & 1;
    int ntile = wave >> 1;
    int col   = ntile * 16 + l15;
    int am    = mtile * 16 + l15;
    float bav = ba[col], bbv = bb[col];
    int cclamp = max(cnt - 1, 0);
    __syncthreads();

    for (int g = 0; g < 4; ++g) {
        int  lrow  = g * 32 + slot;           // local node 0..127
        bool valid = lrow < nn;
        int deg = valid ? nh[lrow] : 0;
        int beg = valid ? min(nscan[lrow], cclamp) : 0;
        int dm = deg;
        dm = max(dm, __shfl_xor(dm, 16));
        dm = max(dm, __shfl_xor(dm, 32));

        float4 agg = make_float4(0.f, 0.f, 0.f, 0.f);
        #define EDGE4(rr, uu, cond)                                              \
        {                                                                        \
            float s = (cond) ? 1.f : 0.f, av = __int_as_float(rr.y);             \
            float e0 = __uint_as_float(uu.x << 16);                              \
            float e1 = __uint_as_float(uu.x & 0xFFFF0000u);                      \
            float e2 = __uint_as_float(uu.y << 16);                              \
            float e3 = __uint_as_float(uu.y & 0xFFFF0000u);                      \
            agg.x = fmaf(s, fmaxf(e0 + fmaf(av, wp.x, bp.x), 0.f), agg.x);       \
            agg.y = fmaf(s, fmaxf(e1 + fmaf(av, wp.y, bp.y), 0.f), agg.y);       \
            agg.z = fmaf(s, fmaxf(e2 + fmaf(av, wp.z, bp.z), 0.f), agg.z);       \
            agg.w = fmaf(s, fmaxf(e3 + fmaf(av, wp.w, bp.w), 0.f), agg.w);       \
        }
        for (int j = 0; j < dm; j += 4) {
            int2 r0 = staging[beg + ((j + 0) < deg ? j + 0 : 0)];
            int2 r1 = staging[beg + ((j + 1) < deg ? j + 1 : 0)];
            int2 r2 = staging[beg + ((j + 2) < deg ? j + 2 : 0)];
            int2 r3 = staging[beg + ((j + 3) < deg ? j + 3 : 0)];
            uint2 u0 = g2[(r0.x & 0x1FFFF) * 16 + l15];
            uint2 u1 = g2[(r1.x & 0x1FFFF) * 16 + l15];
            uint2 u2 = g2[(r2.x & 0x1FFFF) * 16 + l15];
            uint2 u3 = g2[(r3.x & 0x1FFFF) * 16 + l15];
            EDGE4(r0, u0, (j + 0) < deg)
            EDGE4(r1, u1, (j + 1) < deg)
            EDGE4(r2, u2, (j + 2) < deg)
            EDGE4(r3, u3, (j + 3) < deg)
        }
        #undef EDGE4
        if (valid) {
            float4 sv = *(const float4*)(self32 + (size_t)(node0 + lrow) * DIM + d0);
            agg.x += sv.x; agg.y += sv.y; agg.z += sv.z; agg.w += sv.w;
        }
        {
            unsigned lov = (unsigned)f2bf(agg.x) | ((unsigned)f2bf(agg.y) << 16);
            unsigned hiv = (unsigned)f2bf(agg.z) | ((unsigned)f2bf(agg.w) << 16);
            *(uint2*)&h16[slot * PAD + d0] = make_uint2(lov, hiv);
        }
        __syncthreads();

        f32x4 acc = {bav, bav, bav, bav};
        #pragma unroll
        for (int s = 0; s < 2; ++s) {
            bf16x8 a = *(const bf16x8*)&h16[am * PAD + s * 32 + quad * 8];
            bf16x8 bb8 = *(const bf16x8*)&sWat[col * PAD + s * 32 + quad * 8];
            acc = __builtin_amdgcn_mfma_f32_16x16x32_bf16(a, bb8, acc, 0, 0, 0);
        }
        #pragma unroll
        for (int rr = 0; rr < 4; ++rr) {
            int row = mtile * 16 + quad * 4 + rr;
            t16[row * PAD + col] = (short)f2bf(fmaxf(acc[rr], 0.f));
        }
        __syncthreads();

        f32x4 acc2 = {bbv, bbv, bbv, bbv};
        #pragma unroll
        for (int s = 0; s < 2; ++s) {
            bf16x8 a = *(const bf16x8*)&t16[am * PAD + s * 32 + quad * 8];
            bf16x8 bb8 = *(const bf16x8*)&sWbt[col * PAD + s * 32 + quad * 8];
            acc2 = __builtin_amdgcn_mfma_f32_16x16x32_bf16(a, bb8, acc2, 0, 0, 0);
        }
        #pragma unroll
        for (int rr = 0; rr < 4; ++rr) {
            int row = mtile * 16 + quad * 4 + rr;
            h16[row * PAD + col] = (short)f2bf(fmaxf(acc2[rr], 0.f));
        }
        __syncthreads();
        {
            int n2 = t >> 4, dd = (t & 15) * 2;
            int lnode = g * 32 + n2;
            if (node0 + lnode < N_NODES) {
                uint2 v = *(const uint2*)&h16[n2 * PAD + dd * 2];
                *(uint2*)&out16[(size_t)(node0 + lnode) * 32 + dd] = v;
            }
        }
        __syncthreads();
    }
}

// ---------------------------------------------------------------------------
// Fused GINE layer (round-7 verbatim) — used for layer 2 only.
// ---------------------------------------------------------------------------
template<bool SELF32>
__global__ __launch_bounds__(512, 8) void gine_mfma(
    const uint2* __restrict__ g2,
    const float* __restrict__ self32,
    const int*   __restrict__ rowptr,
    const int2*  __restrict__ csr_e,
    const float* __restrict__ We, const float* __restrict__ be,
    const float* __restrict__ Wa, const float* __restrict__ ba,
    const float* __restrict__ Wb, const float* __restrict__ bb,
    unsigned int* __restrict__ out16)
{
    __shared__ short sWat[64 * PAD];
    __shared__ short sWbt[64 * PAD];
    __shared__ short h16[32 * PAD];
    __shared__ short t16[32 * PAD];

    int t = threadIdx.x;
    for (int i = t; i < 4096; i += 512) {
        int k = i >> 6, n = i & 63;
        sWat[n * PAD + k] = (short)f2bf(Wa[i]);
        sWbt[n * PAD + k] = (short)f2bf(Wb[i]);
    }
    int wave = t >> 6;
    int lane = t & 63;
    int quad = lane >> 4;
    int l15  = lane & 15;
    int slot = wave * 4 + quad;
    int d0   = l15 * 4;
    float4 wp = *(const float4*)(We + d0);
    float4 bp = *(const float4*)(be + d0);
    int mtile = wave & 1;
    int ntile = wave >> 1;
    int col   = ntile * 16 + l15;
    int am    = mtile * 16 + l15;
    float bav = ba[col], bbv = bb[col];
    __syncthreads();

    for (int base = blockIdx.x * 32; base < N_NODES; base += gridDim.x * 32) {
        int  node  = base + slot;
        bool valid = node < N_NODES;
        int beg = 0, deg = 0;
        if (valid) {
            beg = rowptr[node];
            deg = rowptr[node + 1] - beg;
            beg = min(beg, N_EDGES - 1);
        }
        int dm = deg;
        dm = max(dm, __shfl_xor(dm, 16));
        dm = max(dm, __shfl_xor(dm, 32));

        float4 agg = make_float4(0.f, 0.f, 0.f, 0.f);
        #define EDGE4(rr, uu, cond)                                              \
        {                                                                        \
            float s = (cond) ? 1.f : 0.f, av = __int_as_float(rr.y);             \
            float e0 = __uint_as_float(uu.x << 16);                              \
            float e1 = __uint_as_float(uu.x & 0xFFFF0000u);                      \
            float e2 = __uint_as_float(uu.y << 16);                              \
            float e3 = __uint_as_float(uu.y & 0xFFFF0000u);                      \
            agg.x = fmaf(s, fmaxf(e0 + fmaf(av, wp.x, bp.x), 0.f), agg.x);       \
            agg.y = fmaf(s, fmaxf(e1 + fmaf(av, wp.y, bp.y), 0.f), agg.y);       \
            agg.z = fmaf(s, fmaxf(e2 + fmaf(av, wp.z, bp.z), 0.f), agg.z);       \
            agg.w = fmaf(s, fmaxf(e3 + fmaf(av, wp.w, bp.w), 0.f), agg.w);       \
        }
        for (int j = 0; j < dm; j += 4) {
            int2 r0 = csr_e[beg + ((j + 0) < deg ? j + 0 : 0)];
            int2 r1 = csr_e[beg + ((j + 1) < deg ? j + 1 : 0)];
            int2 r2 = csr_e[beg + ((j + 2) < deg ? j + 2 : 0)];
            int2 r3 = csr_e[beg + ((j + 3) < deg ? j + 3 : 0)];
            uint2 u0 = g2[r0.x + l15];
            uint2 u1 = g2[r1.x + l15];
            uint2 u2 = g2[r2.x + l15];
            uint2 u3 = g2[r3.x + l15];
            EDGE4(r0, u0, (j + 0) < deg)
            EDGE4(r1, u1, (j + 1) < deg)
            EDGE4(r2, u2, (j + 2) < deg)
            EDGE4(r3, u3, (j + 3) < deg)
        }
        #undef EDGE4
        if (valid) {
            if (SELF32) {
                float4 sv = *(const float4*)(self32 + (size_t)node * DIM + d0);
                agg.x += sv.x; agg.y += sv.y; agg.z += sv.z; agg.w += sv.w;
            } else {
                uint2 u = g2[node * 16 + l15];
                agg.x += __uint_as_float(u.x << 16);
                agg.y += __uint_as_float(u.x & 0xFFFF0000u);
                agg.z += __uint_as_float(u.y << 16);
                agg.w += __uint_as_float(u.y & 0xFFFF0000u);
            }
        }
        {
            unsigned lo = (unsigned)f2bf(agg.x) | ((unsigned)f2bf(agg.y) << 16);
            unsigned hi = (unsigned)f2bf(agg.z) | ((unsigned)f2bf(agg.w) << 16);
            *(uint2*)&h16[slot * PAD + d0] = make_uint2(lo, hi);
        }
        __syncthreads();

        f32x4 acc = {bav, bav, bav, bav};
        #pragma unroll
        for (int s = 0; s < 2; ++s) {
            bf16x8 a = *(const bf16x8*)&h16[am * PAD + s * 32 + quad * 8];
            bf16x8 b = *(const bf16x8*)&sWat[col * PAD + s * 32 + quad * 8];
            acc = __builtin_amdgcn_mfma_f32_16x16x32_bf16(a, b, acc, 0, 0, 0);
        }
        #pragma unroll
        for (int r = 0; r < 4; ++r) {
            int row = mtile * 16 + quad * 4 + r;
            t16[row * PAD + col] = (short)f2bf(fmaxf(acc[r], 0.f));
        }
        __syncthreads();

        f32x4 acc2 = {bbv, bbv, bbv, bbv};
        #pragma unroll
        for (int s = 0; s < 2; ++s) {
            bf16x8 a = *(const bf16x8*)&t16[am * PAD + s * 32 + quad * 8];
            bf16x8 b = *(const bf16x8*)&sWbt[col * PAD + s * 32 + quad * 8];
            acc2 = __builtin_amdgcn_mfma_f32_16x16x32_bf16(a, b, acc2, 0, 0, 0);
        }
        #pragma unroll
        for (int r = 0; r < 4; ++r) {
            int row = mtile * 16 + quad * 4 + r;
            h16[row * PAD + col] = (short)f2bf(fmaxf(acc2[r], 0.f));
        }
        __syncthreads();
        {
            int nn = t >> 4, dd = (t & 15) * 2;
            if (base + nn < N_NODES) {
                uint2 v = *(const uint2*)&h16[nn * PAD + dd * 2];
                *(uint2*)&out16[(size_t)(base + nn) * 32 + dd] = v;
            }
        }
        __syncthreads();
    }
}

// ---------------------------------------------------------------------------
// Fused pooling + classifier (unchanged).
// ---------------------------------------------------------------------------
__device__ __forceinline__ int lbound(const int* __restrict__ a, int key) {
    int lo = 0, hi = N_NODES;
    while (lo < hi) {
        int mid = (lo + hi) >> 1;
        if (a[mid] < key) lo = mid + 1; else hi = mid;
    }
    return lo;
}

__global__ __launch_bounds__(256) void pool_cls(
    const unsigned int* __restrict__ B16b,
    const int* __restrict__ batch,
    const float* __restrict__ Wc1,  const float* __restrict__ bc1,
    const float* __restrict__ Wc2,  const float* __restrict__ bc2,
    float* __restrict__ out)
{
    __shared__ float sW[64 * 64];
    __shared__ float sp[4][64];

    int t = threadIdx.x;
    for (int i = t; i < 64 * 64; i += 256) sW[i] = Wc1[i];

    int nl   = t >> 6;
    int lane = t & 63;
    int g    = blockIdx.x * 4 + nl;

    int p = lane & 31, h = lane >> 5;
    if (g < NUM_GRAPHS) {
        int s = lbound(batch, g);
        int e = lbound(batch, g + 1);
        float2 sum = make_float2(0.f, 0.f);
        for (int i = s + h; i < e; i += 2) {
            unsigned u = B16b[(size_t)i * 32 + p];
            sum.x += __uint_as_float(u << 16);
            sum.y += __uint_as_float(u & 0xFFFF0000u);
        }
        sum.x += __shfl_xor(sum.x, 32);
        sum.y += __shfl_xor(sum.y, 32);
        if (h == 0) {
            float inv = 1.f / (float)max(e - s, 1);
            sp[nl][2 * p]     = sum.x * inv;
            sp[nl][2 * p + 1] = sum.y * inv;
        }
    } else if (h == 0) {
        sp[nl][2 * p] = 0.f;
        sp[nl][2 * p + 1] = 0.f;
    }
    __syncthreads();

    float acc = bc1[lane];
    #pragma unroll
    for (int k = 0; k < 64; ++k)
        acc = fmaf(sp[nl][k], sW[k * 64 + lane], acc);
    float tv = fmaxf(acc, 0.f) * Wc2[lane];

    #pragma unroll
    for (int off = 32; off > 0; off >>= 1)
        tv += __shfl_down(tv, off);

    if (lane == 0 && g < NUM_GRAPHS) out[g] = tv + bc2[0];
}

extern "C" void kernel_launch(void* const* d_in, const int* in_sizes, int n_in,
                              void* d_out, int out_size, void* d_ws, size_t ws_size,
                              hipStream_t stream) {
    const float* x     = (const float*)d_in[0];
    const int*   ei    = (const int*)  d_in[1];
    const float* ea    = (const float*)d_in[2];
    const int*   batch = (const int*)  d_in[3];
    const float* W1a = (const float*)d_in[4];
    const float* b1a = (const float*)d_in[5];
    const float* W1b = (const float*)d_in[6];
    const float* b1b = (const float*)d_in[7];
    const float* We1 = (const float*)d_in[8];
    const float* be1 = (const float*)d_in[9];
    const float* W2a = (const float*)d_in[10];
    const float* b2a = (const float*)d_in[11];
    const float* W2b = (const float*)d_in[12];
    const float* b2b = (const float*)d_in[13];
    const float* We2 = (const float*)d_in[14];
    const float* be2 = (const float*)d_in[15];
    const float* Wc1 = (const float*)d_in[16];
    const float* bc1 = (const float*)d_in[17];
    const float* Wc2 = (const float*)d_in[18];
    const float* bc2 = (const float*)d_in[19];

    // workspace layout (~53 MB); tmp aliases B16b (dead until gine layer 2)
    int2*           csr_e  = (int2*)d_ws;                            // [E]
    unsigned short* x16    = (unsigned short*)(csr_e + N_EDGES);     // [N*64]
    unsigned short* B16    = x16 + (size_t)N_NODES * DIM;            // [N*64] h1
    unsigned short* B16b   = B16 + (size_t)N_NODES * DIM;            // [N*64] h2
    int2*           tmp    = (int2*)B16b;                            // [E] alias
    int*            hist   = (int*)(B16b + (size_t)N_NODES * DIM);   // [SLICES*NBUCK]
    int*            off    = hist + SLICES * NBUCK;                  // [NBUCK*SLICES]
    int*            bucketTotal = off + NBUCK * SLICES;              // [NBUCK]
    int*            bucketStart = bucketTotal + NBUCK;               // [NBUCK+1]
    int*            rowptr = bucketStart + (NBUCK + 1);              // [N+1]

    hipMemsetAsync(bucketTotal, 0, NBUCK * sizeof(int), stream);

    // ---- bucket-grouped edge build (c4 fused into gine layer 1) ----
    prep<<<SLICES + CONV_BLK, 256, 0, stream>>>(ei, x, hist, bucketTotal, x16);
    csr_c2a<<<1, 1024, 0, stream>>>(bucketTotal, bucketStart);
    csr_c2b<<<NBUCK, 512, 0, stream>>>(hist, bucketStart, off);
    csr_c3<<<SLICES, 512, 0, stream>>>(ei, ea, hist, off, tmp);

    // ---- layer 1: fused sort + gather + MLP -> B16; emits csr_e/rowptr ----
    gine_sort<<<NBUCK, 512, 0, stream>>>(
        (const uint2*)x16, x, bucketStart, tmp, csr_e, rowptr,
        We1, be1, W1a, b1a, W1b, b1b, (unsigned int*)B16);

    // ---- layer 2: round-7 gine on csr_e -> B16b ----
    gine_mfma<false><<<1024, 512, 0, stream>>>(
        (const uint2*)B16, nullptr, rowptr, csr_e,
        We2, be2, W2a, b2a, W2b, b2b, (unsigned int*)B16b);

    // ---- fused pooling + classifier ----
    pool_cls<<<(NUM_GRAPHS + 3) / 4, 256, 0, stream>>>(
        (const unsigned int*)B16b, batch, Wc1, bc1, Wc2, bc2, (float*)d_out);
}